// Round 9
// baseline (211.880 us; speedup 1.0000x reference)
//
#include <hip/hip_runtime.h>

// MoE-LoRA top-1 dispatch.
//  xe: per (sb,b,e) block (32 rows x full D): barrier-free pool quarter (8 rows)
//      + LDS-staged bf16 MFMA x@A^T -> xr_all bf16.  LDS rows padded to 70 ushorts
//      (35 words, odd) -> <=2-way bank aliasing on all access patterns.
//  router: partials -> MLP -> top/balance ; out: xr[top[b]] @ B^T * 2
constexpr int B_ = 4, S_ = 2048, D_ = 4096, E_ = 4, R_ = 64, OUT_ = 4096;
constexpr int NMOD = 4, NREG = 3, HID_ = 128;
constexpr int RIN_ = D_ + NMOD + NREG;      // 4103
constexpr float SCALING_ = 2.0f;            // alpha/rank
constexpr int NSB_ = 64;                    // xe s-blocks of 32 rows
constexpr int P_   = NSB_ * E_;             // 256 pool strips of 8 rows per b
constexpr int KC_  = 33;                    // router k-chunks of 128 (33*128 >= 4103)

// ws layout (float units) — everything fully written each call, no memset needed
constexpr size_t WS_PP    = 0;                                     // P_*B*D f32 pool partials
constexpr size_t WS_HACC2 = WS_PP + (size_t)P_ * B_ * D_;          // B*KC_*HID f32
constexpr size_t WS_TOP   = WS_HACC2 + B_ * KC_ * HID_;            // B ints
constexpr size_t WS_ABF   = WS_TOP + 16;                           // E*R*D bf16
constexpr size_t WS_BBF   = WS_ABF + (size_t)E_ * R_ * D_ / 2;     // E*OUT*R bf16
constexpr size_t WS_XRB   = WS_BBF + (size_t)E_ * OUT_ * R_ / 2;   // E*B*S*R bf16

using short8 = __attribute__((ext_vector_type(8))) short;
using f32x4  = __attribute__((ext_vector_type(4))) float;

__device__ inline unsigned short f2bf(float f) {  // RNE fp32 -> bf16
    unsigned u = __float_as_uint(f);
    unsigned r = u + 0x7FFFu + ((u >> 16) & 1u);
    return (unsigned short)(r >> 16);
}

__global__ void cvt_w_kernel(const float* __restrict__ A, const float* __restrict__ Bw,
                             ushort* __restrict__ Abf, ushort* __restrict__ Bbf) {
    int i = blockIdx.x * blockDim.x + threadIdx.x;  // float4 id
    constexpr int N4 = E_ * R_ * D_ / 4;            // 262144 per tensor
    if (i < N4) {
        float4 v = ((const float4*)A)[i];
        ((ushort4*)Abf)[i] = make_ushort4(f2bf(v.x), f2bf(v.y), f2bf(v.z), f2bf(v.w));
    } else {
        int j = i - N4;
        float4 v = ((const float4*)Bw)[j];
        ((ushort4*)Bbf)[j] = make_ushort4(f2bf(v.x), f2bf(v.y), f2bf(v.z), f2bf(v.w));
    }
}

// Block (sb,b,e): pool partial over rows [s0+e*8, +8) (barrier-free stream),
// then 32 rows x full D MFMA with single-buffer LDS + register prefetch.
// 4 waves: wave w -> m-tile m=w&1 (16 rows), n-half p=w>>1 (two 16-col n-tiles).
__global__ __launch_bounds__(256, 4) void xe_kernel(const float* __restrict__ x,
                                                    const ushort* __restrict__ Abf,
                                                    float* __restrict__ pp,
                                                    ushort* __restrict__ xr_bf) {
    __shared__ ushort xs[32][70];       // 140B row stride (35 words, odd)
    __shared__ ushort as[64][70];
    int sb = blockIdx.x, b = blockIdx.y, e = blockIdx.z;
    int s0 = sb * 32;
    int t = threadIdx.x, lane = t & 63, w = t >> 6;
    int m = w & 1, p = w >> 1;

    // ---- pool quarter: this block's own 8 rows, pure per-thread stream ----
    {
        const float4* xp = (const float4*)(x + ((size_t)b * S_ + s0 + e * 8) * D_);
        float4 a0 = {0,0,0,0}, a1 = {0,0,0,0}, a2 = {0,0,0,0}, a3 = {0,0,0,0};
#pragma unroll
        for (int r = 0; r < 8; ++r) {
            float4 v0 = xp[(size_t)r * 1024 + t];
            float4 v1 = xp[(size_t)r * 1024 + 256 + t];
            float4 v2 = xp[(size_t)r * 1024 + 512 + t];
            float4 v3 = xp[(size_t)r * 1024 + 768 + t];
            a0.x += v0.x; a0.y += v0.y; a0.z += v0.z; a0.w += v0.w;
            a1.x += v1.x; a1.y += v1.y; a1.z += v1.z; a1.w += v1.w;
            a2.x += v2.x; a2.y += v2.y; a2.z += v2.z; a2.w += v2.w;
            a3.x += v3.x; a3.y += v3.y; a3.z += v3.z; a3.w += v3.w;
        }
        float* ppb = pp + ((size_t)(sb * E_ + e) * B_ + b) * D_;
        *(float4*)&ppb[(t)       * 4] = a0;
        *(float4*)&ppb[(256 + t) * 4] = a1;
        *(float4*)&ppb[(512 + t) * 4] = a2;
        *(float4*)&ppb[(768 + t) * 4] = a3;
    }

    // ---- MFMA k-loop: BK=64, register prefetch of next chunk ----
    const float*  xb = x   + ((size_t)b * S_ + s0) * D_;
    const ushort* Ab = Abf + (size_t)e * R_ * D_;
    int xr_ = t >> 3, xc = t & 7;       // x row, col-oct (8 f32)
    int ar  = t >> 2, ac = (t & 3) * 2; // A row, 2 col-octs (16 bf16)
    float4 xv0 = *(const float4*)(xb + (size_t)xr_ * D_ + xc * 8);
    float4 xv1 = *(const float4*)(xb + (size_t)xr_ * D_ + xc * 8 + 4);
    int4   av0 = *(const int4*)(Ab + (size_t)ar * D_ + ac * 8);
    int4   av1 = *(const int4*)(Ab + (size_t)ar * D_ + (ac + 1) * 8);
    f32x4 acc[2] = {};
    int mrow = m * 16 + (lane & 15);
    int koff = (lane >> 4) * 8;
    for (int kc = 0; kc < D_ / 64; ++kc) {
        __syncthreads();               // previous tile's readers done
        *(ushort4*)&xs[xr_][xc * 8]     = make_ushort4(f2bf(xv0.x), f2bf(xv0.y), f2bf(xv0.z), f2bf(xv0.w));
        *(ushort4*)&xs[xr_][xc * 8 + 4] = make_ushort4(f2bf(xv1.x), f2bf(xv1.y), f2bf(xv1.z), f2bf(xv1.w));
        *(int4*)&as[ar][ac * 8]         = av0;
        *(int4*)&as[ar][(ac + 1) * 8]   = av1;
        __syncthreads();               // tile ready
        if (kc < D_ / 64 - 1) {        // prefetch next chunk into regs
            int k0 = (kc + 1) * 64;
            xv0 = *(const float4*)(xb + (size_t)xr_ * D_ + k0 + xc * 8);
            xv1 = *(const float4*)(xb + (size_t)xr_ * D_ + k0 + xc * 8 + 4);
            av0 = *(const int4*)(Ab + (size_t)ar * D_ + k0 + ac * 8);
            av1 = *(const int4*)(Ab + (size_t)ar * D_ + k0 + (ac + 1) * 8);
        }
#pragma unroll
        for (int kk = 0; kk < 2; ++kk) {
            short8 af = *(const short8*)&xs[mrow][kk * 32 + koff];
#pragma unroll
            for (int n = 0; n < 2; ++n) {
                short8 bf = *(const short8*)&as[(p * 2 + n) * 16 + (lane & 15)][kk * 32 + koff];
                acc[n] = __builtin_amdgcn_mfma_f32_16x16x32_bf16(af, bf, acc[n], 0, 0, 0);
            }
        }
    }
    // C/D: col = lane&15, row = (lane>>4)*4 + i ; write bf16 xr directly
    int col0 = lane & 15;
    int rb   = m * 16 + ((lane >> 4) << 2);
    ushort* xo = xr_bf + (((size_t)e * B_ + b) * S_ + s0) * R_;
#pragma unroll
    for (int n = 0; n < 2; ++n)
#pragma unroll
        for (int i = 0; i < 4; ++i)
            xo[(size_t)(rb + i) * R_ + (p * 2 + n) * 16 + col0] = f2bf(acc[n][i]);
}

// hacc2[b][kc][h] = sum over chunk's 128 k-rows of router_in[k]*w1[k][h]
__global__ __launch_bounds__(256) void router_h_kernel(const float* __restrict__ pp,
                                                       const float* __restrict__ rel,
                                                       const float* __restrict__ reg,
                                                       const float* __restrict__ w1,
                                                       float* __restrict__ hacc2) {
    __shared__ float rin[128];
    __shared__ float red[256];
    int b = blockIdx.x, kc = blockIdx.y;
    int t = threadIdx.x;
    int k0 = kc * 128;
    // parallel partial-sum: thread t covers column k0+(t&127), strip-half (t>>7)
    {
        int k = k0 + (t & 127), half = t >> 7;
        float s = 0.f;
        if (k < D_) {
            for (int pi = half * (P_ / 2); pi < (half + 1) * (P_ / 2); ++pi)
                s += pp[((size_t)pi * B_ + b) * D_ + k];
        }
        red[t] = s;
    }
    __syncthreads();
    if (t < 128) {
        int k = k0 + t;
        float v = 0.f;
        if (k < D_)               v = (red[t] + red[t + 128]) * (1.0f / S_);
        else if (k < D_ + NMOD)   v = rel[b * NMOD + (k - D_)];
        else if (k < RIN_)        v = reg[b * NREG + (k - D_ - NMOD)];
        rin[t] = v;
    }
    __syncthreads();
    int h = t & 127, half = t >> 7;
    float acc = 0.f;
#pragma unroll 8
    for (int i = 0; i < 64; ++i) {
        int kk = 2 * i + half;
        int k = k0 + kk;
        if (k < RIN_) acc += rin[kk] * w1[(size_t)k * HID_ + h];
    }
    red[t] = acc;
    __syncthreads();
    if (t < 128)
        hacc2[((size_t)b * KC_ + kc) * HID_ + t] = red[t] + red[t + 128];
}

__global__ void router_finish_kernel(const float* __restrict__ hacc2, const float* __restrict__ b1,
                                     const float* __restrict__ w2, const float* __restrict__ b2,
                                     int* __restrict__ top, float* __restrict__ bal_out) {
    __shared__ float h_lds[B_][HID_];
    __shared__ float logit[B_][E_];
    __shared__ float probs[B_][E_];
    int t = threadIdx.x; // 128
    for (int b = 0; b < B_; ++b) {
        float v = b1[t];
        for (int j = 0; j < KC_; ++j) v += hacc2[((size_t)b * KC_ + j) * HID_ + t];
        float u = 0.7978845608028654f * (v + 0.044715f * v * v * v); // tanh-GELU
        h_lds[b][t] = 0.5f * v * (1.0f + tanhf(u));
    }
    __syncthreads();
    if (t < B_ * E_) {
        int b = t >> 2, e = t & 3;
        float acc = b2[e];
        for (int j = 0; j < HID_; ++j) acc += h_lds[b][j] * w2[j * E_ + e];
        logit[b][e] = acc;
    }
    __syncthreads();
    if (t < B_) {
        int b = t;
        float mx = logit[b][0]; int arg = 0;
        for (int e = 1; e < E_; ++e) if (logit[b][e] > mx) { mx = logit[b][e]; arg = e; }
        float s = 0.f, pv[E_];
        for (int e = 0; e < E_; ++e) { pv[e] = expf(logit[b][e] - mx); s += pv[e]; }
        for (int e = 0; e < E_; ++e) probs[b][e] = pv[e] / s;
        top[b] = arg;
    }
    __syncthreads();
    if (t == 0) {
        float bal = 0.f;
        for (int e = 0; e < E_; ++e) {
            float avg = 0.25f * (probs[0][e] + probs[1][e] + probs[2][e] + probs[3][e]);
            bal += avg * avg;
        }
        *bal_out = 0.01f * E_ * bal;
    }
}

// out[b,s,o] = 2 * sum_r xr_bf[top[b]][b,s,r] * B_bf[e,o,r]
__global__ __launch_bounds__(256) void out_kernel(const ushort* __restrict__ xr_bf,
                                                  const ushort* __restrict__ Bbf,
                                                  const int* __restrict__ top,
                                                  float* __restrict__ out) {
    __shared__ ushort xrs[64][70];
    __shared__ ushort bs[128][70];
    int b  = blockIdx.z;
    int e  = top[b];
    int s0 = blockIdx.x * 64, o0 = blockIdx.y * 128;
    int t = threadIdx.x, lane = t & 63, w = t >> 6;
    const ushort* xrb = xr_bf + (((size_t)e * B_ + b) * S_ + s0) * R_;
#pragma unroll
    for (int i = 0; i < 2; ++i) {                   // stage xr 64x64 bf16
        int lin = t + 256 * i; int row = lin >> 3, cq = lin & 7;
        int4 v = *(const int4*)(xrb + (size_t)row * R_ + cq * 8);
        *(int4*)&xrs[row][cq * 8] = v;
    }
    const ushort* Bb = Bbf + (size_t)e * OUT_ * R_ + (size_t)o0 * R_;
#pragma unroll
    for (int i = 0; i < 4; ++i) {                   // stage B 128x64 bf16
        int lin = t + 256 * i; int row = lin >> 3, cq = lin & 7;
        int4 v = *(const int4*)(Bb + (size_t)row * R_ + cq * 8);
        *(int4*)&bs[row][cq * 8] = v;
    }
    __syncthreads();
    int mrow = w * 16 + (lane & 15);
    int koff = (lane >> 4) * 8;
    f32x4 acc[8] = {};
#pragma unroll
    for (int kk = 0; kk < 2; ++kk) {
        short8 af = *(const short8*)&xrs[mrow][kk * 32 + koff];
#pragma unroll
        for (int n = 0; n < 8; ++n) {
            short8 bf = *(const short8*)&bs[n * 16 + (lane & 15)][kk * 32 + koff];
            acc[n] = __builtin_amdgcn_mfma_f32_16x16x32_bf16(af, bf, acc[n], 0, 0, 0);
        }
    }
    int col0  = lane & 15;
    int rbase = (lane >> 4) << 2;
    float* ob = out + ((size_t)b * S_ + s0 + w * 16) * OUT_ + o0;
#pragma unroll
    for (int n = 0; n < 8; ++n)
#pragma unroll
        for (int i = 0; i < 4; ++i)
            ob[(size_t)(rbase + i) * OUT_ + n * 16 + col0] = acc[n][i] * SCALING_;
}

extern "C" void kernel_launch(void* const* d_in, const int* in_sizes, int n_in,
                              void* d_out, int out_size, void* d_ws, size_t ws_size,
                              hipStream_t stream) {
    const float* x   = (const float*)d_in[0];
    const float* rel = (const float*)d_in[1];
    const float* reg = (const float*)d_in[2];
    const float* lA  = (const float*)d_in[3];
    const float* lB  = (const float*)d_in[4];
    const float* w1  = (const float*)d_in[5];
    const float* b1  = (const float*)d_in[6];
    const float* w2  = (const float*)d_in[7];
    const float* b2  = (const float*)d_in[8];
    float* out = (float*)d_out;
    float* ws  = (float*)d_ws;

    float*  pp    = ws + WS_PP;
    float*  hacc2 = ws + WS_HACC2;
    int*    top   = (int*)(ws + WS_TOP);
    ushort* Abf   = (ushort*)(ws + WS_ABF);
    ushort* Bbf   = (ushort*)(ws + WS_BBF);
    ushort* xrb   = (ushort*)(ws + WS_XRB);

    cvt_w_kernel<<<2 * (E_ * R_ * D_ / 4) / 256, 256, 0, stream>>>(lA, lB, Abf, Bbf);
    xe_kernel<<<dim3(NSB_, B_, E_), 256, 0, stream>>>(x, Abf, pp, xrb);
    router_h_kernel<<<dim3(B_, KC_), 256, 0, stream>>>(pp, rel, reg, w1, hacc2);
    router_finish_kernel<<<1, 128, 0, stream>>>(hacc2, b1, w2, b2, top,
                                                out + (size_t)out_size - 1);
    out_kernel<<<dim3(S_ / 64, OUT_ / 128, B_), 256, 0, stream>>>(xrb, Bbf, top, out);
}

// Round 10
// 143.125 us; speedup vs baseline: 1.4804x; 1.4804x over previous
//
#include <hip/hip_runtime.h>

// MoE-LoRA top-1 dispatch — selected-expert pipeline (R3 topology, repaired):
//  zero_xr + cvt_w + pool(partials) -> router -> xr(top[b], K-split x8, atomic f32) -> out
constexpr int B_ = 4, S_ = 2048, D_ = 4096, E_ = 4, R_ = 64, OUT_ = 4096;
constexpr int NMOD = 4, NREG = 3, HID_ = 128;
constexpr int RIN_ = D_ + NMOD + NREG;      // 4103
constexpr float SCALING_ = 2.0f;            // alpha/rank
constexpr int P_   = 128;                   // pool strips of 16 rows
constexpr int KSP_ = 8, KCH_ = D_ / KSP_;   // xr K-split chunks of 512
constexpr int KC_  = 33;                    // router k-chunks of 128 (33*128 >= 4103)

// ws layout (float units)
constexpr size_t WS_PP    = 0;                                     // P_*B*D f32 pool partials
constexpr size_t WS_HACC2 = WS_PP + (size_t)P_ * B_ * D_;          // B*KC_*HID f32
constexpr size_t WS_TOP   = WS_HACC2 + B_ * KC_ * HID_;            // B ints
constexpr size_t WS_ABF   = WS_TOP + 16;                           // E*R*D bf16
constexpr size_t WS_BBF   = WS_ABF + (size_t)E_ * R_ * D_ / 2;     // E*OUT*R bf16
constexpr size_t WS_XR    = WS_BBF + (size_t)E_ * OUT_ * R_ / 2;   // B*S*R f32 (zeroed, atomic)

using short8 = __attribute__((ext_vector_type(8))) short;
using f32x4  = __attribute__((ext_vector_type(4))) float;

__device__ inline unsigned short f2bf(float f) {  // RNE fp32 -> bf16
    unsigned u = __float_as_uint(f);
    unsigned r = u + 0x7FFFu + ((u >> 16) & 1u);
    return (unsigned short)(r >> 16);
}

__global__ __launch_bounds__(256) void zero_xr_kernel(float* __restrict__ xr) {
    int i = blockIdx.x * 256 + threadIdx.x;          // float4 id, B*S*R/4 = 131072
    ((float4*)xr)[i] = make_float4(0.f, 0.f, 0.f, 0.f);
}

__global__ void cvt_w_kernel(const float* __restrict__ A, const float* __restrict__ Bw,
                             ushort* __restrict__ Abf, ushort* __restrict__ Bbf) {
    int i = blockIdx.x * blockDim.x + threadIdx.x;  // float4 id
    constexpr int N4 = E_ * R_ * D_ / 4;            // 262144 per tensor
    if (i < N4) {
        float4 v = ((const float4*)A)[i];
        ((ushort4*)Abf)[i] = make_ushort4(f2bf(v.x), f2bf(v.y), f2bf(v.z), f2bf(v.w));
    } else {
        int j = i - N4;
        float4 v = ((const float4*)Bw)[j];
        ((ushort4*)Bbf)[j] = make_ushort4(f2bf(v.x), f2bf(v.y), f2bf(v.z), f2bf(v.w));
    }
}

// Pool partials: strip = 16 rows; thread t sums col-quads t and t+512. Pure stream.
__global__ __launch_bounds__(512) void pool_kernel(const float* __restrict__ x,
                                                   float* __restrict__ pp) {
    int strip = blockIdx.x, b = blockIdx.y;
    int t = threadIdx.x;
    const float4* xp = (const float4*)(x + ((size_t)b * S_ + strip * 16) * D_);
    float4 a0 = {0,0,0,0}, a1 = {0,0,0,0};
#pragma unroll 4
    for (int r = 0; r < 16; ++r) {
        float4 v0 = xp[(size_t)r * 1024 + t];
        float4 v1 = xp[(size_t)r * 1024 + 512 + t];
        a0.x += v0.x; a0.y += v0.y; a0.z += v0.z; a0.w += v0.w;
        a1.x += v1.x; a1.y += v1.y; a1.z += v1.z; a1.w += v1.w;
    }
    float* ppb = pp + ((size_t)strip * B_ + b) * D_;
    *(float4*)&ppb[t * 4]         = a0;
    *(float4*)&ppb[(512 + t) * 4] = a1;
}

// hacc2[b][kc][h] = sum over chunk's 128 k-rows of router_in[k]*w1[k][h]
__global__ __launch_bounds__(256) void router_h_kernel(const float* __restrict__ pp,
                                                       const float* __restrict__ rel,
                                                       const float* __restrict__ reg,
                                                       const float* __restrict__ w1,
                                                       float* __restrict__ hacc2) {
    __shared__ float rin[128];
    __shared__ float red[256];
    int b = blockIdx.x, kc = blockIdx.y;
    int t = threadIdx.x;
    int k0 = kc * 128;
    {   // parallel partial reduce over the 128 strips (two halves of 64)
        int k = k0 + (t & 127), half = t >> 7;
        float s = 0.f;
        if (k < D_) {
            for (int pi = half * 64; pi < half * 64 + 64; ++pi)
                s += pp[((size_t)pi * B_ + b) * D_ + k];
        }
        red[t] = s;
    }
    __syncthreads();
    if (t < 128) {
        int k = k0 + t;
        float v = 0.f;
        if (k < D_)               v = (red[t] + red[t + 128]) * (1.0f / S_);
        else if (k < D_ + NMOD)   v = rel[b * NMOD + (k - D_)];
        else if (k < RIN_)        v = reg[b * NREG + (k - D_ - NMOD)];
        rin[t] = v;
    }
    __syncthreads();
    int h = t & 127, half = t >> 7;
    float acc = 0.f;
#pragma unroll 8
    for (int i = 0; i < 64; ++i) {
        int kk = 2 * i + half;
        int k = k0 + kk;
        if (k < RIN_) acc += rin[kk] * w1[(size_t)k * HID_ + h];
    }
    red[t] = acc;
    __syncthreads();
    if (t < 128)
        hacc2[((size_t)b * KC_ + kc) * HID_ + t] = red[t] + red[t + 128];
}

__global__ void router_finish_kernel(const float* __restrict__ hacc2, const float* __restrict__ b1,
                                     const float* __restrict__ w2, const float* __restrict__ b2,
                                     int* __restrict__ top, float* __restrict__ bal_out) {
    __shared__ float h_lds[B_][HID_];
    __shared__ float logit[B_][E_];
    __shared__ float probs[B_][E_];
    int t = threadIdx.x; // 128
    for (int b = 0; b < B_; ++b) {
        float v = b1[t];
        for (int j = 0; j < KC_; ++j) v += hacc2[((size_t)b * KC_ + j) * HID_ + t];
        float u = 0.7978845608028654f * (v + 0.044715f * v * v * v); // tanh-GELU
        h_lds[b][t] = 0.5f * v * (1.0f + tanhf(u));
    }
    __syncthreads();
    if (t < B_ * E_) {
        int b = t >> 2, e = t & 3;
        float acc = b2[e];
        for (int j = 0; j < HID_; ++j) acc += h_lds[b][j] * w2[j * E_ + e];
        logit[b][e] = acc;
    }
    __syncthreads();
    if (t < B_) {
        int b = t;
        float mx = logit[b][0]; int arg = 0;
        for (int e = 1; e < E_; ++e) if (logit[b][e] > mx) { mx = logit[b][e]; arg = e; }
        float s = 0.f, pv[E_];
        for (int e = 0; e < E_; ++e) { pv[e] = expf(logit[b][e] - mx); s += pv[e]; }
        for (int e = 0; e < E_; ++e) probs[b][e] = pv[e] / s;
        top[b] = arg;
    }
    __syncthreads();
    if (t == 0) {
        float bal = 0.f;
        for (int e = 0; e < E_; ++e) {
            float avg = 0.25f * (probs[0][e] + probs[1][e] + probs[2][e] + probs[3][e]);
            bal += avg * avg;
        }
        *bal_out = 0.01f * E_ * bal;
    }
}

// xr[b,s,r] += sum_{K-slice} x[b,s,k] * A_bf[top[b],r,k]   (selected expert, K-split x8)
// 1024 short blocks (8 iters each), 4 waves, reg-prefetch, [70]-odd LDS padding.
__global__ __launch_bounds__(256) void xr_kernel(const float* __restrict__ x,
                                                 const ushort* __restrict__ Abf,
                                                 const int* __restrict__ top,
                                                 float* __restrict__ xr) {
    __shared__ ushort xs[64][70];   // 140B row stride (35 words, odd)
    __shared__ ushort as[64][70];
    int sb = blockIdx.x, b = blockIdx.y, kq = blockIdx.z;
    int e  = top[b];
    int s0 = sb * 64;
    int t = threadIdx.x, lane = t & 63, w = t >> 6;
    const float*  xb = x   + ((size_t)b * S_ + s0) * D_;
    const ushort* Ab = Abf + (size_t)e * R_ * D_;
    int xrw = t >> 4, xfq = t & 15;     // x stage: rows xrw+16i, quad xfq
    int arw = t >> 3, acq = t & 7;      // A stage: rows arw+32i, oct acq
    int kz = kq * KCH_;
    // prologue loads (kc = 0)
    float4 xv[4]; int4 av[2];
#pragma unroll
    for (int i = 0; i < 4; ++i)
        xv[i] = *(const float4*)(xb + (size_t)(xrw + 16 * i) * D_ + kz + xfq * 4);
#pragma unroll
    for (int i = 0; i < 2; ++i)
        av[i] = *(const int4*)(Ab + (size_t)(arw + 32 * i) * D_ + kz + acq * 8);
    f32x4 acc[4] = {};
    int mrow = w * 16 + (lane & 15);
    int koff = (lane >> 4) * 8;
    for (int kc = 0; kc < KCH_ / 64; ++kc) {
        __syncthreads();               // previous tile's readers done
#pragma unroll
        for (int i = 0; i < 4; ++i)
            *(ushort4*)&xs[xrw + 16 * i][xfq * 4] =
                make_ushort4(f2bf(xv[i].x), f2bf(xv[i].y), f2bf(xv[i].z), f2bf(xv[i].w));
#pragma unroll
        for (int i = 0; i < 2; ++i)
            *(int4*)&as[arw + 32 * i][acq * 8] = av[i];
        __syncthreads();               // tile ready
        if (kc < KCH_ / 64 - 1) {      // prefetch next chunk into regs
            int k0 = kz + (kc + 1) * 64;
#pragma unroll
            for (int i = 0; i < 4; ++i)
                xv[i] = *(const float4*)(xb + (size_t)(xrw + 16 * i) * D_ + k0 + xfq * 4);
#pragma unroll
            for (int i = 0; i < 2; ++i)
                av[i] = *(const int4*)(Ab + (size_t)(arw + 32 * i) * D_ + k0 + acq * 8);
        }
#pragma unroll
        for (int kk = 0; kk < 2; ++kk) {
            short8 af = *(const short8*)&xs[mrow][kk * 32 + koff];
#pragma unroll
            for (int n = 0; n < 4; ++n) {
                short8 bf = *(const short8*)&as[n * 16 + (lane & 15)][kk * 32 + koff];
                acc[n] = __builtin_amdgcn_mfma_f32_16x16x32_bf16(af, bf, acc[n], 0, 0, 0);
            }
        }
    }
    // C/D: col = lane&15, row = (lane>>4)*4 + i
    int col0  = lane & 15;
    int rbase = w * 16 + ((lane >> 4) << 2);
#pragma unroll
    for (int n = 0; n < 4; ++n)
#pragma unroll
        for (int i = 0; i < 4; ++i)
            atomicAdd(&xr[((size_t)b * S_ + s0 + rbase + i) * R_ + n * 16 + col0], acc[n][i]);
}

// out[b,s,o] = 2 * sum_r xr[b,s,r] * B_bf[top[b],o,r]
__global__ __launch_bounds__(256) void out_kernel(const float* __restrict__ xr,
                                                  const ushort* __restrict__ Bbf,
                                                  const int* __restrict__ top,
                                                  float* __restrict__ out) {
    __shared__ ushort xrs[64][70];
    __shared__ ushort bs[128][70];
    int b  = blockIdx.z;
    int e  = top[b];
    int s0 = blockIdx.x * 64, o0 = blockIdx.y * 128;
    int t = threadIdx.x, lane = t & 63, w = t >> 6;
#pragma unroll
    for (int i = 0; i < 4; ++i) {                   // stage xr 64x64 f32 -> bf16
        int lin = t + 256 * i; int row = lin >> 4, fq = lin & 15;
        float4 v = *(const float4*)(xr + ((size_t)b * S_ + s0 + row) * R_ + fq * 4);
        *(ushort4*)&xrs[row][fq * 4] = make_ushort4(f2bf(v.x), f2bf(v.y), f2bf(v.z), f2bf(v.w));
    }
    const ushort* Bb = Bbf + (size_t)e * OUT_ * R_ + (size_t)o0 * R_;
#pragma unroll
    for (int i = 0; i < 4; ++i) {                   // stage B 128x64 bf16
        int lin = t + 256 * i; int row = lin >> 3, cq = lin & 7;
        int4 v = *(const int4*)(Bb + (size_t)row * R_ + cq * 8);
        *(int4*)&bs[row][cq * 8] = v;
    }
    __syncthreads();
    int mrow = w * 16 + (lane & 15);
    int koff = (lane >> 4) * 8;
    f32x4 acc[8] = {};
#pragma unroll
    for (int kk = 0; kk < 2; ++kk) {
        short8 af = *(const short8*)&xrs[mrow][kk * 32 + koff];
#pragma unroll
        for (int n = 0; n < 8; ++n) {
            short8 bf = *(const short8*)&bs[n * 16 + (lane & 15)][kk * 32 + koff];
            acc[n] = __builtin_amdgcn_mfma_f32_16x16x32_bf16(af, bf, acc[n], 0, 0, 0);
        }
    }
    int col0  = lane & 15;
    int rbase = (lane >> 4) << 2;
    float* ob = out + ((size_t)b * S_ + s0 + w * 16) * OUT_ + o0;
#pragma unroll
    for (int n = 0; n < 8; ++n)
#pragma unroll
        for (int i = 0; i < 4; ++i)
            ob[(size_t)(rbase + i) * OUT_ + n * 16 + col0] = acc[n][i] * SCALING_;
}

extern "C" void kernel_launch(void* const* d_in, const int* in_sizes, int n_in,
                              void* d_out, int out_size, void* d_ws, size_t ws_size,
                              hipStream_t stream) {
    const float* x   = (const float*)d_in[0];
    const float* rel = (const float*)d_in[1];
    const float* reg = (const float*)d_in[2];
    const float* lA  = (const float*)d_in[3];
    const float* lB  = (const float*)d_in[4];
    const float* w1  = (const float*)d_in[5];
    const float* b1  = (const float*)d_in[6];
    const float* w2  = (const float*)d_in[7];
    const float* b2  = (const float*)d_in[8];
    float* out = (float*)d_out;
    float* ws  = (float*)d_ws;

    float*  pp    = ws + WS_PP;
    float*  hacc2 = ws + WS_HACC2;
    int*    top   = (int*)(ws + WS_TOP);
    ushort* Abf   = (ushort*)(ws + WS_ABF);
    ushort* Bbf   = (ushort*)(ws + WS_BBF);
    float*  xrp   = ws + WS_XR;

    zero_xr_kernel<<<B_ * S_ * R_ / 4 / 256, 256, 0, stream>>>(xrp);
    cvt_w_kernel<<<2 * (E_ * R_ * D_ / 4) / 256, 256, 0, stream>>>(lA, lB, Abf, Bbf);
    pool_kernel<<<dim3(P_, B_), 512, 0, stream>>>(x, pp);
    router_h_kernel<<<dim3(B_, KC_), 256, 0, stream>>>(pp, rel, reg, w1, hacc2);
    router_finish_kernel<<<1, 128, 0, stream>>>(hacc2, b1, w2, b2, top,
                                                out + (size_t)out_size - 1);
    xr_kernel<<<dim3(S_ / 64, B_, KSP_), 256, 0, stream>>>(x, Abf, top, xrp);
    out_kernel<<<dim3(S_ / 64, OUT_ / 128, B_), 256, 0, stream>>>(xrp, Bbf, top, out);
}

// Round 11
// 120.992 us; speedup vs baseline: 1.7512x; 1.1829x over previous
//
#include <hip/hip_runtime.h>

// MoE-LoRA top-1 dispatch — consolidated selected-expert pipeline:
//  prep (pool partials + weight cvt + xr zero, one barrier-free launch)
//  -> router_h -> router_finish -> xr (top[b], K-split x8, dbuf LDS, atomic f32) -> out
constexpr int B_ = 4, S_ = 2048, D_ = 4096, E_ = 4, R_ = 64, OUT_ = 4096;
constexpr int NMOD = 4, NREG = 3, HID_ = 128;
constexpr int RIN_ = D_ + NMOD + NREG;      // 4103
constexpr float SCALING_ = 2.0f;            // alpha/rank
constexpr int P_   = 128;                   // pool strips of 16 rows
constexpr int KSP_ = 8, KCH_ = D_ / KSP_;   // xr K-split chunks of 512
constexpr int KC_  = 33;                    // router k-chunks of 128 (33*128 >= 4103)

// ws layout (float units)
constexpr size_t WS_PP    = 0;                                     // P_*B*D f32 pool partials
constexpr size_t WS_HACC2 = WS_PP + (size_t)P_ * B_ * D_;          // B*KC_*HID f32
constexpr size_t WS_TOP   = WS_HACC2 + B_ * KC_ * HID_;            // B ints
constexpr size_t WS_ABF   = WS_TOP + 16;                           // E*R*D bf16
constexpr size_t WS_BBF   = WS_ABF + (size_t)E_ * R_ * D_ / 2;     // E*OUT*R bf16
constexpr size_t WS_XR    = WS_BBF + (size_t)E_ * OUT_ * R_ / 2;   // B*S*R f32 (zeroed, atomic)

using short8 = __attribute__((ext_vector_type(8))) short;
using f32x4  = __attribute__((ext_vector_type(4))) float;

__device__ inline unsigned short f2bf(float f) {  // RNE fp32 -> bf16
    unsigned u = __float_as_uint(f);
    unsigned r = u + 0x7FFFu + ((u >> 16) & 1u);
    return (unsigned short)(r >> 16);
}

// One launch, three barrier-free jobs selected by block range:
//  [0,512):    pool partials, strip = bx>>2 (16 rows), b = bx&3
//  [512,1024): weight f32->bf16 cvt (A then B), 1024 float4 per block
//  [1024,1152): zero xr accumulator, 1024 float4 per block
__global__ __launch_bounds__(256) void prep_kernel(const float* __restrict__ x,
                                                   const float* __restrict__ A,
                                                   const float* __restrict__ Bw,
                                                   float* __restrict__ pp,
                                                   ushort* __restrict__ Abf,
                                                   ushort* __restrict__ Bbf,
                                                   float* __restrict__ xr) {
    int bx = blockIdx.x, t = threadIdx.x;
    if (bx < 512) {
        int strip = bx >> 2, b = bx & 3;
        const float4* xp = (const float4*)(x + ((size_t)b * S_ + strip * 16) * D_);
        float4 a0 = {0,0,0,0}, a1 = {0,0,0,0}, a2 = {0,0,0,0}, a3 = {0,0,0,0};
#pragma unroll 4
        for (int r = 0; r < 16; ++r) {
            float4 v0 = xp[(size_t)r * 1024 + t];
            float4 v1 = xp[(size_t)r * 1024 + 256 + t];
            float4 v2 = xp[(size_t)r * 1024 + 512 + t];
            float4 v3 = xp[(size_t)r * 1024 + 768 + t];
            a0.x += v0.x; a0.y += v0.y; a0.z += v0.z; a0.w += v0.w;
            a1.x += v1.x; a1.y += v1.y; a1.z += v1.z; a1.w += v1.w;
            a2.x += v2.x; a2.y += v2.y; a2.z += v2.z; a2.w += v2.w;
            a3.x += v3.x; a3.y += v3.y; a3.z += v3.z; a3.w += v3.w;
        }
        float* ppb = pp + ((size_t)strip * B_ + b) * D_;
        *(float4*)&ppb[(t)       * 4] = a0;
        *(float4*)&ppb[(256 + t) * 4] = a1;
        *(float4*)&ppb[(512 + t) * 4] = a2;
        *(float4*)&ppb[(768 + t) * 4] = a3;
    } else if (bx < 1024) {
        constexpr int N4 = E_ * R_ * D_ / 4;        // 262144 per tensor
        int base = (bx - 512) * 1024;
#pragma unroll
        for (int j = 0; j < 4; ++j) {
            int i = base + t + j * 256;
            if (i < N4) {
                float4 v = ((const float4*)A)[i];
                ((ushort4*)Abf)[i] = make_ushort4(f2bf(v.x), f2bf(v.y), f2bf(v.z), f2bf(v.w));
            } else {
                int k = i - N4;
                float4 v = ((const float4*)Bw)[k];
                ((ushort4*)Bbf)[k] = make_ushort4(f2bf(v.x), f2bf(v.y), f2bf(v.z), f2bf(v.w));
            }
        }
    } else {
        int base = (bx - 1024) * 1024;
#pragma unroll
        for (int j = 0; j < 4; ++j)
            ((float4*)xr)[base + t + j * 256] = make_float4(0.f, 0.f, 0.f, 0.f);
    }
}

// hacc2[b][kc][h] = sum over chunk's 128 k-rows of router_in[k]*w1[k][h]
__global__ __launch_bounds__(256) void router_h_kernel(const float* __restrict__ pp,
                                                       const float* __restrict__ rel,
                                                       const float* __restrict__ reg,
                                                       const float* __restrict__ w1,
                                                       float* __restrict__ hacc2) {
    __shared__ float rin[128];
    __shared__ float red[256];
    int b = blockIdx.x, kc = blockIdx.y;
    int t = threadIdx.x;
    int k0 = kc * 128;
    {   // parallel partial reduce over the 128 strips (two halves of 64)
        int k = k0 + (t & 127), half = t >> 7;
        float s = 0.f;
        if (k < D_) {
            for (int pi = half * 64; pi < half * 64 + 64; ++pi)
                s += pp[((size_t)pi * B_ + b) * D_ + k];
        }
        red[t] = s;
    }
    __syncthreads();
    if (t < 128) {
        int k = k0 + t;
        float v = 0.f;
        if (k < D_)               v = (red[t] + red[t + 128]) * (1.0f / S_);
        else if (k < D_ + NMOD)   v = rel[b * NMOD + (k - D_)];
        else if (k < RIN_)        v = reg[b * NREG + (k - D_ - NMOD)];
        rin[t] = v;
    }
    __syncthreads();
    int h = t & 127, half = t >> 7;
    float acc = 0.f;
#pragma unroll 8
    for (int i = 0; i < 64; ++i) {
        int kk = 2 * i + half;
        int k = k0 + kk;
        if (k < RIN_) acc += rin[kk] * w1[(size_t)k * HID_ + h];
    }
    red[t] = acc;
    __syncthreads();
    if (t < 128)
        hacc2[((size_t)b * KC_ + kc) * HID_ + t] = red[t] + red[t + 128];
}

__global__ void router_finish_kernel(const float* __restrict__ hacc2, const float* __restrict__ b1,
                                     const float* __restrict__ w2, const float* __restrict__ b2,
                                     int* __restrict__ top, float* __restrict__ bal_out) {
    __shared__ float h_lds[B_][HID_];
    __shared__ float logit[B_][E_];
    __shared__ float probs[B_][E_];
    int t = threadIdx.x; // 128
    for (int b = 0; b < B_; ++b) {
        float v = b1[t];
        for (int j = 0; j < KC_; ++j) v += hacc2[((size_t)b * KC_ + j) * HID_ + t];
        float u = 0.7978845608028654f * (v + 0.044715f * v * v * v); // tanh-GELU
        h_lds[b][t] = 0.5f * v * (1.0f + tanhf(u));
    }
    __syncthreads();
    if (t < B_ * E_) {
        int b = t >> 2, e = t & 3;
        float acc = b2[e];
        for (int j = 0; j < HID_; ++j) acc += h_lds[b][j] * w2[j * E_ + e];
        logit[b][e] = acc;
    }
    __syncthreads();
    if (t < B_) {
        int b = t;
        float mx = logit[b][0]; int arg = 0;
        for (int e = 1; e < E_; ++e) if (logit[b][e] > mx) { mx = logit[b][e]; arg = e; }
        float s = 0.f, pv[E_];
        for (int e = 0; e < E_; ++e) { pv[e] = expf(logit[b][e] - mx); s += pv[e]; }
        for (int e = 0; e < E_; ++e) probs[b][e] = pv[e] / s;
        top[b] = arg;
    }
    __syncthreads();
    if (t == 0) {
        float bal = 0.f;
        for (int e = 0; e < E_; ++e) {
            float avg = 0.25f * (probs[0][e] + probs[1][e] + probs[2][e] + probs[3][e]);
            bal += avg * avg;
        }
        *bal_out = 0.01f * E_ * bal;
    }
}

// xr[b,s,r] += sum_{K-slice} x[b,s,k] * A_bf[top[b],r,k]   (selected expert, K-split x8)
// Double-buffered LDS: ONE barrier per K-chunk. [70]-odd padding. 8 chunks/block.
__global__ __launch_bounds__(256) void xr_kernel(const float* __restrict__ x,
                                                 const ushort* __restrict__ Abf,
                                                 const int* __restrict__ top,
                                                 float* __restrict__ xr) {
    __shared__ ushort xs[2][64][70];   // 140B row stride (35 words, odd)
    __shared__ ushort as[2][64][70];
    int sb = blockIdx.x, b = blockIdx.y, kq = blockIdx.z;
    int e  = top[b];
    int s0 = sb * 64;
    int t = threadIdx.x, lane = t & 63, w = t >> 6;
    const float*  xb = x   + ((size_t)b * S_ + s0) * D_;
    const ushort* Ab = Abf + (size_t)e * R_ * D_;
    int xrw = t >> 4, xfq = t & 15;     // x stage: rows xrw+16i, quad xfq
    int arw = t >> 3, acq = t & 7;      // A stage: rows arw+32i, oct acq
    int kz = kq * KCH_;
    float4 xv[4]; int4 av[2];
#pragma unroll
    for (int i = 0; i < 4; ++i)
        xv[i] = *(const float4*)(xb + (size_t)(xrw + 16 * i) * D_ + kz + xfq * 4);
#pragma unroll
    for (int i = 0; i < 2; ++i)
        av[i] = *(const int4*)(Ab + (size_t)(arw + 32 * i) * D_ + kz + acq * 8);
    f32x4 acc[4] = {};
    int mrow = w * 16 + (lane & 15);
    int koff = (lane >> 4) * 8;
    for (int kc = 0; kc < KCH_ / 64; ++kc) {
        int cur = kc & 1;
#pragma unroll
        for (int i = 0; i < 4; ++i)
            *(ushort4*)&xs[cur][xrw + 16 * i][xfq * 4] =
                make_ushort4(f2bf(xv[i].x), f2bf(xv[i].y), f2bf(xv[i].z), f2bf(xv[i].w));
#pragma unroll
        for (int i = 0; i < 2; ++i)
            *(int4*)&as[cur][arw + 32 * i][acq * 8] = av[i];
        __syncthreads();               // tile cur ready; prev tile's readers drained
        if (kc < KCH_ / 64 - 1) {      // prefetch next chunk into regs (in flight across MFMA)
            int k0 = kz + (kc + 1) * 64;
#pragma unroll
            for (int i = 0; i < 4; ++i)
                xv[i] = *(const float4*)(xb + (size_t)(xrw + 16 * i) * D_ + k0 + xfq * 4);
#pragma unroll
            for (int i = 0; i < 2; ++i)
                av[i] = *(const int4*)(Ab + (size_t)(arw + 32 * i) * D_ + k0 + acq * 8);
        }
#pragma unroll
        for (int kk = 0; kk < 2; ++kk) {
            short8 af = *(const short8*)&xs[cur][mrow][kk * 32 + koff];
#pragma unroll
            for (int n = 0; n < 4; ++n) {
                short8 bf = *(const short8*)&as[cur][n * 16 + (lane & 15)][kk * 32 + koff];
                acc[n] = __builtin_amdgcn_mfma_f32_16x16x32_bf16(af, bf, acc[n], 0, 0, 0);
            }
        }
    }
    // C/D: col = lane&15, row = (lane>>4)*4 + i
    int col0  = lane & 15;
    int rbase = w * 16 + ((lane >> 4) << 2);
#pragma unroll
    for (int n = 0; n < 4; ++n)
#pragma unroll
        for (int i = 0; i < 4; ++i)
            atomicAdd(&xr[((size_t)b * S_ + s0 + rbase + i) * R_ + n * 16 + col0], acc[n][i]);
}

// out[b,s,o] = 2 * sum_r xr[b,s,r] * B_bf[top[b],o,r]
__global__ __launch_bounds__(256) void out_kernel(const float* __restrict__ xr,
                                                  const ushort* __restrict__ Bbf,
                                                  const int* __restrict__ top,
                                                  float* __restrict__ out) {
    __shared__ ushort xrs[64][70];
    __shared__ ushort bs[128][70];
    int b  = blockIdx.z;
    int e  = top[b];
    int s0 = blockIdx.x * 64, o0 = blockIdx.y * 128;
    int t = threadIdx.x, lane = t & 63, w = t >> 6;
#pragma unroll
    for (int i = 0; i < 4; ++i) {                   // stage xr 64x64 f32 -> bf16
        int lin = t + 256 * i; int row = lin >> 4, fq = lin & 15;
        float4 v = *(const float4*)(xr + ((size_t)b * S_ + s0 + row) * R_ + fq * 4);
        *(ushort4*)&xrs[row][fq * 4] = make_ushort4(f2bf(v.x), f2bf(v.y), f2bf(v.z), f2bf(v.w));
    }
    const ushort* Bb = Bbf + (size_t)e * OUT_ * R_ + (size_t)o0 * R_;
#pragma unroll
    for (int i = 0; i < 4; ++i) {                   // stage B 128x64 bf16
        int lin = t + 256 * i; int row = lin >> 3, cq = lin & 7;
        int4 v = *(const int4*)(Bb + (size_t)row * R_ + cq * 8);
        *(int4*)&bs[row][cq * 8] = v;
    }
    __syncthreads();
    int mrow = w * 16 + (lane & 15);
    int koff = (lane >> 4) * 8;
    f32x4 acc[8] = {};
#pragma unroll
    for (int kk = 0; kk < 2; ++kk) {
        short8 af = *(const short8*)&xrs[mrow][kk * 32 + koff];
#pragma unroll
        for (int n = 0; n < 8; ++n) {
            short8 bf = *(const short8*)&bs[n * 16 + (lane & 15)][kk * 32 + koff];
            acc[n] = __builtin_amdgcn_mfma_f32_16x16x32_bf16(af, bf, acc[n], 0, 0, 0);
        }
    }
    int col0  = lane & 15;
    int rbase = (lane >> 4) << 2;
    float* ob = out + ((size_t)b * S_ + s0 + w * 16) * OUT_ + o0;
#pragma unroll
    for (int n = 0; n < 8; ++n)
#pragma unroll
        for (int i = 0; i < 4; ++i)
            ob[(size_t)(rbase + i) * OUT_ + n * 16 + col0] = acc[n][i] * SCALING_;
}

extern "C" void kernel_launch(void* const* d_in, const int* in_sizes, int n_in,
                              void* d_out, int out_size, void* d_ws, size_t ws_size,
                              hipStream_t stream) {
    const float* x   = (const float*)d_in[0];
    const float* rel = (const float*)d_in[1];
    const float* reg = (const float*)d_in[2];
    const float* lA  = (const float*)d_in[3];
    const float* lB  = (const float*)d_in[4];
    const float* w1  = (const float*)d_in[5];
    const float* b1  = (const float*)d_in[6];
    const float* w2  = (const float*)d_in[7];
    const float* b2  = (const float*)d_in[8];
    float* out = (float*)d_out;
    float* ws  = (float*)d_ws;

    float*  pp    = ws + WS_PP;
    float*  hacc2 = ws + WS_HACC2;
    int*    top   = (int*)(ws + WS_TOP);
    ushort* Abf   = (ushort*)(ws + WS_ABF);
    ushort* Bbf   = (ushort*)(ws + WS_BBF);
    float*  xrp   = ws + WS_XR;

    prep_kernel<<<1152, 256, 0, stream>>>(x, lA, lB, pp, Abf, Bbf, xrp);
    router_h_kernel<<<dim3(B_, KC_), 256, 0, stream>>>(pp, rel, reg, w1, hacc2);
    router_finish_kernel<<<1, 128, 0, stream>>>(hacc2, b1, w2, b2, top,
                                                out + (size_t)out_size - 1);
    xr_kernel<<<dim3(S_ / 64, B_, KSP_), 256, 0, stream>>>(x, Abf, top, xrp);
    out_kernel<<<dim3(S_ / 64, OUT_ / 128, B_), 256, 0, stream>>>(xrp, Bbf, top, out);
}

// Round 13
// 113.324 us; speedup vs baseline: 1.8697x; 1.0677x over previous
//
#include <hip/hip_runtime.h>

// MoE-LoRA top-1 dispatch — fused selected-expert pipeline:
//  prep (pool partials + A/B frag-pack cvt, one barrier-free launch)
//  -> router_h -> router_finish -> xrout (x@A^T -> in-LDS xr -> @B^T -> out, fused)
constexpr int B_ = 4, S_ = 2048, D_ = 4096, E_ = 4, R_ = 64, OUT_ = 4096;
constexpr int NMOD = 4, NREG = 3, HID_ = 128;
constexpr int RIN_ = D_ + NMOD + NREG;      // 4103
constexpr float SCALING_ = 2.0f;            // alpha/rank
constexpr int P_   = 128;                   // pool strips of 16 rows
constexpr int KC_  = 33;                    // router k-chunks of 128 (33*128 >= 4103)

// ws layout (float units)
constexpr size_t WS_PP    = 0;                                     // P_*B*D f32 pool partials
constexpr size_t WS_HACC2 = WS_PP + (size_t)P_ * B_ * D_;          // B*KC_*HID f32
constexpr size_t WS_TOP   = WS_HACC2 + B_ * KC_ * HID_;            // B ints
constexpr size_t WS_APK   = WS_TOP + 16;                           // E*R*D bf16 frag-packed
constexpr size_t WS_BPK   = WS_APK + (size_t)E_ * R_ * D_ / 2;     // E*OUT*R bf16 frag-packed

using short8 = __attribute__((ext_vector_type(8))) short;
using f32x4  = __attribute__((ext_vector_type(4))) float;
union frag_u { int4 i4; short8 s8; };

__device__ inline unsigned short f2bf(float f) {  // RNE fp32 -> bf16
    unsigned u = __float_as_uint(f);
    unsigned r = u + 0x7FFFu + ((u >> 16) & 1u);
    return (unsigned short)(r >> 16);
}

// One launch, three barrier-free jobs:
//  [0,512):     pool partials, strip = bx>>2 (16 rows), b = bx&3
//  [512,1024):  Apack[((e*128+ks)*4+n)*64+l][j] = A[e][n*16+(l&15)][ks*32+(l>>4)*8+j]
//  [1024,1536): Bpack[((e*256+nt)*2+kk)*64+l][j] = B[e][nt*16+(l&15)][kk*32+(l>>4)*8+j]
__global__ __launch_bounds__(256) void prep_kernel(const float* __restrict__ x,
                                                   const float* __restrict__ A,
                                                   const float* __restrict__ Bw,
                                                   float* __restrict__ pp,
                                                   ushort* __restrict__ Apk,
                                                   ushort* __restrict__ Bpk) {
    int bx = blockIdx.x, t = threadIdx.x;
    if (bx < 512) {
        int strip = bx >> 2, b = bx & 3;
        const float4* xp = (const float4*)(x + ((size_t)b * S_ + strip * 16) * D_);
        float4 a0 = {0,0,0,0}, a1 = {0,0,0,0}, a2 = {0,0,0,0}, a3 = {0,0,0,0};
#pragma unroll 4
        for (int r = 0; r < 16; ++r) {
            float4 v0 = xp[(size_t)r * 1024 + t];
            float4 v1 = xp[(size_t)r * 1024 + 256 + t];
            float4 v2 = xp[(size_t)r * 1024 + 512 + t];
            float4 v3 = xp[(size_t)r * 1024 + 768 + t];
            a0.x += v0.x; a0.y += v0.y; a0.z += v0.z; a0.w += v0.w;
            a1.x += v1.x; a1.y += v1.y; a1.z += v1.z; a1.w += v1.w;
            a2.x += v2.x; a2.y += v2.y; a2.z += v2.z; a2.w += v2.w;
            a3.x += v3.x; a3.y += v3.y; a3.z += v3.z; a3.w += v3.w;
        }
        float* ppb = pp + ((size_t)strip * B_ + b) * D_;
        *(float4*)&ppb[(t)       * 4] = a0;
        *(float4*)&ppb[(256 + t) * 4] = a1;
        *(float4*)&ppb[(512 + t) * 4] = a2;
        *(float4*)&ppb[(768 + t) * 4] = a3;
    } else if (bx < 1024) {
        int idx = (bx - 512) * 256 + t;              // E*128*4*64 = 131072
        int l = idx & 63, n = (idx >> 6) & 3, ks = (idx >> 8) & 127, e = idx >> 15;
        const float* src = A + ((size_t)e * R_ + n * 16 + (l & 15)) * D_
                             + ks * 32 + (l >> 4) * 8;
        float4 v0 = *(const float4*)(src);
        float4 v1 = *(const float4*)(src + 4);
        ushort* dst = Apk + (size_t)idx * 8;
        *(ushort4*)(dst)     = make_ushort4(f2bf(v0.x), f2bf(v0.y), f2bf(v0.z), f2bf(v0.w));
        *(ushort4*)(dst + 4) = make_ushort4(f2bf(v1.x), f2bf(v1.y), f2bf(v1.z), f2bf(v1.w));
    } else {
        int idx = (bx - 1024) * 256 + t;             // E*256*2*64 = 131072
        int l = idx & 63, kk = (idx >> 6) & 1, nt = (idx >> 7) & 255, e = idx >> 15;
        const float* src = Bw + ((size_t)e * OUT_ + nt * 16 + (l & 15)) * R_
                              + kk * 32 + (l >> 4) * 8;
        float4 v0 = *(const float4*)(src);
        float4 v1 = *(const float4*)(src + 4);
        ushort* dst = Bpk + (size_t)idx * 8;
        *(ushort4*)(dst)     = make_ushort4(f2bf(v0.x), f2bf(v0.y), f2bf(v0.z), f2bf(v0.w));
        *(ushort4*)(dst + 4) = make_ushort4(f2bf(v1.x), f2bf(v1.y), f2bf(v1.z), f2bf(v1.w));
    }
}

// hacc2[b][kc][h] = sum over chunk's 128 k-rows of router_in[k]*w1[k][h]
__global__ __launch_bounds__(256) void router_h_kernel(const float* __restrict__ pp,
                                                       const float* __restrict__ rel,
                                                       const float* __restrict__ reg,
                                                       const float* __restrict__ w1,
                                                       float* __restrict__ hacc2) {
    __shared__ float rin[128];
    __shared__ float red[256];
    int b = blockIdx.x, kc = blockIdx.y;
    int t = threadIdx.x;
    int k0 = kc * 128;
    {
        int k = k0 + (t & 127), half = t >> 7;
        float s = 0.f;
        if (k < D_) {
            for (int pi = half * 64; pi < half * 64 + 64; ++pi)
                s += pp[((size_t)pi * B_ + b) * D_ + k];
        }
        red[t] = s;
    }
    __syncthreads();
    if (t < 128) {
        int k = k0 + t;
        float v = 0.f;
        if (k < D_)               v = (red[t] + red[t + 128]) * (1.0f / S_);
        else if (k < D_ + NMOD)   v = rel[b * NMOD + (k - D_)];
        else if (k < RIN_)        v = reg[b * NREG + (k - D_ - NMOD)];
        rin[t] = v;
    }
    __syncthreads();
    int h = t & 127, half = t >> 7;
    float acc = 0.f;
#pragma unroll 8
    for (int i = 0; i < 64; ++i) {
        int kk = 2 * i + half;
        int k = k0 + kk;
        if (k < RIN_) acc += rin[kk] * w1[(size_t)k * HID_ + h];
    }
    red[t] = acc;
    __syncthreads();
    if (t < 128)
        hacc2[((size_t)b * KC_ + kc) * HID_ + t] = red[t] + red[t + 128];
}

__global__ void router_finish_kernel(const float* __restrict__ hacc2, const float* __restrict__ b1,
                                     const float* __restrict__ w2, const float* __restrict__ b2,
                                     int* __restrict__ top, float* __restrict__ bal_out) {
    __shared__ float h_lds[B_][HID_];
    __shared__ float logit[B_][E_];
    __shared__ float probs[B_][E_];
    int t = threadIdx.x; // 128
    for (int b = 0; b < B_; ++b) {
        float v = b1[t];
        for (int j = 0; j < KC_; ++j) v += hacc2[((size_t)b * KC_ + j) * HID_ + t];
        float u = 0.7978845608028654f * (v + 0.044715f * v * v * v); // tanh-GELU
        h_lds[b][t] = 0.5f * v * (1.0f + tanhf(u));
    }
    __syncthreads();
    if (t < B_ * E_) {
        int b = t >> 2, e = t & 3;
        float acc = b2[e];
        for (int j = 0; j < HID_; ++j) acc += h_lds[b][j] * w2[j * E_ + e];
        logit[b][e] = acc;
    }
    __syncthreads();
    if (t < B_) {
        int b = t;
        float mx = logit[b][0]; int arg = 0;
        for (int e = 1; e < E_; ++e) if (logit[b][e] > mx) { mx = logit[b][e]; arg = e; }
        float s = 0.f, pv[E_];
        for (int e = 0; e < E_; ++e) { pv[e] = expf(logit[b][e] - mx); s += pv[e]; }
        for (int e = 0; e < E_; ++e) probs[b][e] = pv[e] / s;
        top[b] = arg;
    }
    __syncthreads();
    if (t == 0) {
        float bal = 0.f;
        for (int e = 0; e < E_; ++e) {
            float avg = 0.25f * (probs[0][e] + probs[1][e] + probs[2][e] + probs[3][e]);
            bal += avg * avg;
        }
        *bal_out = 0.01f * E_ * bal;
    }
}

// Fused xr+out. Block (sb,b): 32 s-rows. 8 waves = (kslice w>>1) x (m-half w&1).
// Phase 1 (NO barriers): wave-private LDS x-staging; A frags coalesced from Apack.
// Reduce K-slices in LDS (2 barriers). Phase 2: out = xr_lds @ Bpack^T * 2, streamed.
__global__ __launch_bounds__(512) void xrout_kernel(const float* __restrict__ x,
                                                    const ushort* __restrict__ Apk,
                                                    const ushort* __restrict__ Bpk,
                                                    const int* __restrict__ top,
                                                    float* __restrict__ out) {
    __shared__ ushort xsw[8][16][70];   // wave-private x half-tiles (140B rows)
    __shared__ float  red[4][2][16][68];// K-slice partials
    __shared__ ushort xs2[32][70];      // reduced xr tile, bf16
    int sb = blockIdx.x, b = blockIdx.y;
    int e  = top[b];
    int s0 = sb * 32;
    int t = threadIdx.x, l = t & 63, w = t >> 6;
    int h = w & 1, ksl = w >> 1;
    int kb = ksl * 1024;

    // ---- phase 1: xr partial for rows [s0+h*16, +16), k in [kb, kb+1024) ----
    const float* xb = x + ((size_t)b * S_ + s0 + h * 16) * D_;
    const int4*  ap = (const int4*)Apk + (size_t)e * 128 * 4 * 64 + l;
    f32x4 acc[4] = {};
    int lr = l >> 4, lc = l & 15;       // load: rows lr+4j, col-quad lc
    for (int i = 0; i < 16; ++i) {
        int k0 = kb + i * 64;
        float4 xv[4];
#pragma unroll
        for (int j = 0; j < 4; ++j)
            xv[j] = *(const float4*)(xb + (size_t)(lr + 4 * j) * D_ + k0 + lc * 4);
#pragma unroll
        for (int j = 0; j < 4; ++j)
            *(ushort4*)&xsw[w][lr + 4 * j][lc * 4] =
                make_ushort4(f2bf(xv[j].x), f2bf(xv[j].y), f2bf(xv[j].z), f2bf(xv[j].w));
        // frags: row l&15, k-cols kk*32+(l>>4)*8 (same-wave ds order via lgkmcnt)
#pragma unroll
        for (int kk = 0; kk < 2; ++kk) {
            short8 xf = *(const short8*)&xsw[w][l & 15][kk * 32 + (l >> 4) * 8];
            int ksg = ksl * 32 + i * 2 + kk;
#pragma unroll
            for (int n = 0; n < 4; ++n) {
                frag_u af; af.i4 = ap[((size_t)ksg * 4 + n) * 64];
                acc[n] = __builtin_amdgcn_mfma_f32_16x16x32_bf16(xf, af.s8, acc[n], 0, 0, 0);
            }
        }
    }
    // write K-slice partial (C/D layout: row (l>>4)*4+i, col n*16+(l&15))
#pragma unroll
    for (int n = 0; n < 4; ++n)
#pragma unroll
        for (int i = 0; i < 4; ++i)
            red[ksl][h][(l >> 4) * 4 + i][n * 16 + (l & 15)] = acc[n][i];
    __syncthreads();
    // reduce 4 K-slices -> bf16 xr tile
    {
        int row = t >> 4, c4 = (t & 15) * 4;
        int hh = row >> 4, r16 = row & 15;
        float4 s = *(const float4*)&red[0][hh][r16][c4];
#pragma unroll
        for (int ks = 1; ks < 4; ++ks) {
            float4 r = *(const float4*)&red[ks][hh][r16][c4];
            s.x += r.x; s.y += r.y; s.z += r.z; s.w += r.w;
        }
        *(ushort4*)&xs2[row][c4] = make_ushort4(f2bf(s.x), f2bf(s.y), f2bf(s.z), f2bf(s.w));
    }
    __syncthreads();

    // ---- phase 2: out[32 rows][w*512 .. +512) = xr @ B^T * 2 ----
    short8 xf2[2][2];
#pragma unroll
    for (int m = 0; m < 2; ++m)
#pragma unroll
        for (int kk = 0; kk < 2; ++kk)
            xf2[m][kk] = *(const short8*)&xs2[m * 16 + (l & 15)][kk * 32 + (l >> 4) * 8];
    const int4* bp = (const int4*)Bpk + (size_t)e * 256 * 2 * 64 + l;
    float* ob = out + ((size_t)b * S_ + s0) * OUT_ + w * 512;
    int ro = (l >> 4) * 4, co = l & 15;
#pragma unroll 4
    for (int ntl = 0; ntl < 32; ++ntl) {
        int nt = w * 32 + ntl;
        frag_u bf0, bf1;
        bf0.i4 = bp[((size_t)nt * 2 + 0) * 64];
        bf1.i4 = bp[((size_t)nt * 2 + 1) * 64];
        f32x4 a2[2] = {};
#pragma unroll
        for (int m = 0; m < 2; ++m) {
            a2[m] = __builtin_amdgcn_mfma_f32_16x16x32_bf16(xf2[m][0], bf0.s8, a2[m], 0, 0, 0);
            a2[m] = __builtin_amdgcn_mfma_f32_16x16x32_bf16(xf2[m][1], bf1.s8, a2[m], 0, 0, 0);
        }
#pragma unroll
        for (int m = 0; m < 2; ++m)
#pragma unroll
            for (int i = 0; i < 4; ++i)
                ob[(size_t)(m * 16 + ro + i) * OUT_ + ntl * 16 + co] = a2[m][i] * SCALING_;
    }
}

extern "C" void kernel_launch(void* const* d_in, const int* in_sizes, int n_in,
                              void* d_out, int out_size, void* d_ws, size_t ws_size,
                              hipStream_t stream) {
    const float* x   = (const float*)d_in[0];
    const float* rel = (const float*)d_in[1];
    const float* reg = (const float*)d_in[2];
    const float* lA  = (const float*)d_in[3];
    const float* lB  = (const float*)d_in[4];
    const float* w1  = (const float*)d_in[5];
    const float* b1  = (const float*)d_in[6];
    const float* w2  = (const float*)d_in[7];
    const float* b2  = (const float*)d_in[8];
    float* out = (float*)d_out;
    float* ws  = (float*)d_ws;

    float*  pp    = ws + WS_PP;
    float*  hacc2 = ws + WS_HACC2;
    int*    top   = (int*)(ws + WS_TOP);
    ushort* Apk   = (ushort*)(ws + WS_APK);
    ushort* Bpk   = (ushort*)(ws + WS_BPK);

    prep_kernel<<<1536, 256, 0, stream>>>(x, lA, lB, pp, Apk, Bpk);
    router_h_kernel<<<dim3(B_, KC_), 256, 0, stream>>>(pp, rel, reg, w1, hacc2);
    router_finish_kernel<<<1, 128, 0, stream>>>(hacc2, b1, w2, b2, top,
                                                out + (size_t)out_size - 1);
    xrout_kernel<<<dim3(S_ / 32, B_), 512, 0, stream>>>(x, Apk, Bpk, top, out);
}

// Round 14
// 104.910 us; speedup vs baseline: 2.0196x; 1.0802x over previous
//
#include <hip/hip_runtime.h>

// MoE-LoRA top-1 dispatch — fused selected-expert pipeline:
//  prep (pool partials + A/B frag-pack cvt, one barrier-free launch)
//  -> router_h -> router_finish -> xrout (x@A^T -> in-LDS xr -> @B^T -> out, fused)
//  xrout v2: 16-row blocks, 512 blocks (2/CU), wave = one 512-wide K-slice.
constexpr int B_ = 4, S_ = 2048, D_ = 4096, E_ = 4, R_ = 64, OUT_ = 4096;
constexpr int NMOD = 4, NREG = 3, HID_ = 128;
constexpr int RIN_ = D_ + NMOD + NREG;      // 4103
constexpr float SCALING_ = 2.0f;            // alpha/rank
constexpr int P_   = 128;                   // pool strips of 16 rows
constexpr int KC_  = 33;                    // router k-chunks of 128 (33*128 >= 4103)

// ws layout (float units)
constexpr size_t WS_PP    = 0;                                     // P_*B*D f32 pool partials
constexpr size_t WS_HACC2 = WS_PP + (size_t)P_ * B_ * D_;          // B*KC_*HID f32
constexpr size_t WS_TOP   = WS_HACC2 + B_ * KC_ * HID_;            // B ints
constexpr size_t WS_APK   = WS_TOP + 16;                           // E*R*D bf16 frag-packed
constexpr size_t WS_BPK   = WS_APK + (size_t)E_ * R_ * D_ / 2;     // E*OUT*R bf16 frag-packed

using short8 = __attribute__((ext_vector_type(8))) short;
using f32x4  = __attribute__((ext_vector_type(4))) float;
union frag_u { int4 i4; short8 s8; };

__device__ inline unsigned short f2bf(float f) {  // RNE fp32 -> bf16
    unsigned u = __float_as_uint(f);
    unsigned r = u + 0x7FFFu + ((u >> 16) & 1u);
    return (unsigned short)(r >> 16);
}

// One launch, three barrier-free jobs:
//  [0,512):     pool partials, strip = bx>>2 (16 rows), b = bx&3
//  [512,1024):  Apack[((e*128+ks)*4+n)*64+l][j] = A[e][n*16+(l&15)][ks*32+(l>>4)*8+j]
//  [1024,1536): Bpack[((e*256+nt)*2+kk)*64+l][j] = B[e][nt*16+(l&15)][kk*32+(l>>4)*8+j]
__global__ __launch_bounds__(256) void prep_kernel(const float* __restrict__ x,
                                                   const float* __restrict__ A,
                                                   const float* __restrict__ Bw,
                                                   float* __restrict__ pp,
                                                   ushort* __restrict__ Apk,
                                                   ushort* __restrict__ Bpk) {
    int bx = blockIdx.x, t = threadIdx.x;
    if (bx < 512) {
        int strip = bx >> 2, b = bx & 3;
        const float4* xp = (const float4*)(x + ((size_t)b * S_ + strip * 16) * D_);
        float4 a0 = {0,0,0,0}, a1 = {0,0,0,0}, a2 = {0,0,0,0}, a3 = {0,0,0,0};
#pragma unroll 4
        for (int r = 0; r < 16; ++r) {
            float4 v0 = xp[(size_t)r * 1024 + t];
            float4 v1 = xp[(size_t)r * 1024 + 256 + t];
            float4 v2 = xp[(size_t)r * 1024 + 512 + t];
            float4 v3 = xp[(size_t)r * 1024 + 768 + t];
            a0.x += v0.x; a0.y += v0.y; a0.z += v0.z; a0.w += v0.w;
            a1.x += v1.x; a1.y += v1.y; a1.z += v1.z; a1.w += v1.w;
            a2.x += v2.x; a2.y += v2.y; a2.z += v2.z; a2.w += v2.w;
            a3.x += v3.x; a3.y += v3.y; a3.z += v3.z; a3.w += v3.w;
        }
        float* ppb = pp + ((size_t)strip * B_ + b) * D_;
        *(float4*)&ppb[(t)       * 4] = a0;
        *(float4*)&ppb[(256 + t) * 4] = a1;
        *(float4*)&ppb[(512 + t) * 4] = a2;
        *(float4*)&ppb[(768 + t) * 4] = a3;
    } else if (bx < 1024) {
        int idx = (bx - 512) * 256 + t;              // E*128*4*64 = 131072
        int l = idx & 63, n = (idx >> 6) & 3, ks = (idx >> 8) & 127, e = idx >> 15;
        const float* src = A + ((size_t)e * R_ + n * 16 + (l & 15)) * D_
                             + ks * 32 + (l >> 4) * 8;
        float4 v0 = *(const float4*)(src);
        float4 v1 = *(const float4*)(src + 4);
        ushort* dst = Apk + (size_t)idx * 8;
        *(ushort4*)(dst)     = make_ushort4(f2bf(v0.x), f2bf(v0.y), f2bf(v0.z), f2bf(v0.w));
        *(ushort4*)(dst + 4) = make_ushort4(f2bf(v1.x), f2bf(v1.y), f2bf(v1.z), f2bf(v1.w));
    } else {
        int idx = (bx - 1024) * 256 + t;             // E*256*2*64 = 131072
        int l = idx & 63, kk = (idx >> 6) & 1, nt = (idx >> 7) & 255, e = idx >> 15;
        const float* src = Bw + ((size_t)e * OUT_ + nt * 16 + (l & 15)) * R_
                              + kk * 32 + (l >> 4) * 8;
        float4 v0 = *(const float4*)(src);
        float4 v1 = *(const float4*)(src + 4);
        ushort* dst = Bpk + (size_t)idx * 8;
        *(ushort4*)(dst)     = make_ushort4(f2bf(v0.x), f2bf(v0.y), f2bf(v0.z), f2bf(v0.w));
        *(ushort4*)(dst + 4) = make_ushort4(f2bf(v1.x), f2bf(v1.y), f2bf(v1.z), f2bf(v1.w));
    }
}

// hacc2[b][kc][h] = sum over chunk's 128 k-rows of router_in[k]*w1[k][h]
__global__ __launch_bounds__(256) void router_h_kernel(const float* __restrict__ pp,
                                                       const float* __restrict__ rel,
                                                       const float* __restrict__ reg,
                                                       const float* __restrict__ w1,
                                                       float* __restrict__ hacc2) {
    __shared__ float rin[128];
    __shared__ float red[256];
    int b = blockIdx.x, kc = blockIdx.y;
    int t = threadIdx.x;
    int k0 = kc * 128;
    {
        int k = k0 + (t & 127), half = t >> 7;
        float s = 0.f;
        if (k < D_) {
            for (int pi = half * 64; pi < half * 64 + 64; ++pi)
                s += pp[((size_t)pi * B_ + b) * D_ + k];
        }
        red[t] = s;
    }
    __syncthreads();
    if (t < 128) {
        int k = k0 + t;
        float v = 0.f;
        if (k < D_)               v = (red[t] + red[t + 128]) * (1.0f / S_);
        else if (k < D_ + NMOD)   v = rel[b * NMOD + (k - D_)];
        else if (k < RIN_)        v = reg[b * NREG + (k - D_ - NMOD)];
        rin[t] = v;
    }
    __syncthreads();
    int h = t & 127, half = t >> 7;
    float acc = 0.f;
#pragma unroll 8
    for (int i = 0; i < 64; ++i) {
        int kk = 2 * i + half;
        int k = k0 + kk;
        if (k < RIN_) acc += rin[kk] * w1[(size_t)k * HID_ + h];
    }
    red[t] = acc;
    __syncthreads();
    if (t < 128)
        hacc2[((size_t)b * KC_ + kc) * HID_ + t] = red[t] + red[t + 128];
}

__global__ void router_finish_kernel(const float* __restrict__ hacc2, const float* __restrict__ b1,
                                     const float* __restrict__ w2, const float* __restrict__ b2,
                                     int* __restrict__ top, float* __restrict__ bal_out) {
    __shared__ float h_lds[B_][HID_];
    __shared__ float logit[B_][E_];
    __shared__ float probs[B_][E_];
    int t = threadIdx.x; // 128
    for (int b = 0; b < B_; ++b) {
        float v = b1[t];
        for (int j = 0; j < KC_; ++j) v += hacc2[((size_t)b * KC_ + j) * HID_ + t];
        float u = 0.7978845608028654f * (v + 0.044715f * v * v * v); // tanh-GELU
        h_lds[b][t] = 0.5f * v * (1.0f + tanhf(u));
    }
    __syncthreads();
    if (t < B_ * E_) {
        int b = t >> 2, e = t & 3;
        float acc = b2[e];
        for (int j = 0; j < HID_; ++j) acc += h_lds[b][j] * w2[j * E_ + e];
        logit[b][e] = acc;
    }
    __syncthreads();
    if (t < B_) {
        int b = t;
        float mx = logit[b][0]; int arg = 0;
        for (int e = 1; e < E_; ++e) if (logit[b][e] > mx) { mx = logit[b][e]; arg = e; }
        float s = 0.f, pv[E_];
        for (int e = 0; e < E_; ++e) { pv[e] = expf(logit[b][e] - mx); s += pv[e]; }
        for (int e = 0; e < E_; ++e) probs[b][e] = pv[e] / s;
        top[b] = arg;
    }
    __syncthreads();
    if (t == 0) {
        float bal = 0.f;
        for (int e = 0; e < E_; ++e) {
            float avg = 0.25f * (probs[0][e] + probs[1][e] + probs[2][e] + probs[3][e]);
            bal += avg * avg;
        }
        *bal_out = 0.01f * E_ * bal;
    }
}

// Fused xr+out, v2. Block (sb,b): 16 s-rows; 8 waves, wave w = K-slice [w*512,(w+1)*512).
// Phase 1 (NO barriers): wave-private LDS x-staging; A frags coalesced from Apack;
// each wave accumulates all 4 n-tiles over its K-slice. Reduce 8 slices (2 barriers).
// Phase 2: out[16 rows][w*512 ..+512) = xr_lds @ Bpack^T * 2, streamed.
__global__ __launch_bounds__(512) void xrout_kernel(const float* __restrict__ x,
                                                    const ushort* __restrict__ Apk,
                                                    const ushort* __restrict__ Bpk,
                                                    const int* __restrict__ top,
                                                    float* __restrict__ out) {
    __shared__ ushort xsw[8][16][70];   // wave-private x tiles (140B rows)
    __shared__ float  red[8][16][68];   // K-slice partials
    __shared__ ushort xs2[16][70];      // reduced xr tile, bf16
    int sb = blockIdx.x, b = blockIdx.y;
    int e  = top[b];
    int s0 = sb * 16;
    int t = threadIdx.x, l = t & 63, w = t >> 6;
    int kb = w * 512;

    // ---- phase 1: xr partial for all 16 rows, k in [kb, kb+512) ----
    const float* xb = x + ((size_t)b * S_ + s0) * D_;
    const int4*  ap = (const int4*)Apk + (size_t)e * 128 * 4 * 64 + l;
    f32x4 acc[4] = {};
    int lr = l >> 4, lc = l & 15;       // load: rows lr+4j, col-quad lc
    for (int i = 0; i < 8; ++i) {
        int k0 = kb + i * 64;
        float4 xv[4];
#pragma unroll
        for (int j = 0; j < 4; ++j)
            xv[j] = *(const float4*)(xb + (size_t)(lr + 4 * j) * D_ + k0 + lc * 4);
#pragma unroll
        for (int j = 0; j < 4; ++j)
            *(ushort4*)&xsw[w][lr + 4 * j][lc * 4] =
                make_ushort4(f2bf(xv[j].x), f2bf(xv[j].y), f2bf(xv[j].z), f2bf(xv[j].w));
        // frags: row l&15, k-cols kk*32+(l>>4)*8 (same-wave ds order via lgkmcnt)
#pragma unroll
        for (int kk = 0; kk < 2; ++kk) {
            short8 xf = *(const short8*)&xsw[w][l & 15][kk * 32 + (l >> 4) * 8];
            int ksg = w * 16 + i * 2 + kk;
#pragma unroll
            for (int n = 0; n < 4; ++n) {
                frag_u af; af.i4 = ap[((size_t)ksg * 4 + n) * 64];
                acc[n] = __builtin_amdgcn_mfma_f32_16x16x32_bf16(xf, af.s8, acc[n], 0, 0, 0);
            }
        }
    }
    // write K-slice partial (C/D layout: row (l>>4)*4+i, col n*16+(l&15))
#pragma unroll
    for (int n = 0; n < 4; ++n)
#pragma unroll
        for (int i = 0; i < 4; ++i)
            red[w][(l >> 4) * 4 + i][n * 16 + (l & 15)] = acc[n][i];
    __syncthreads();
    // reduce 8 K-slices -> bf16 xr tile (512 threads x 2 cols)
    {
        int row = t >> 5, c2 = (t & 31) * 2;
        float s0f = red[0][row][c2], s1f = red[0][row][c2 + 1];
#pragma unroll
        for (int ks = 1; ks < 8; ++ks) {
            s0f += red[ks][row][c2];
            s1f += red[ks][row][c2 + 1];
        }
        xs2[row][c2]     = f2bf(s0f);
        xs2[row][c2 + 1] = f2bf(s1f);
    }
    __syncthreads();

    // ---- phase 2: out[16 rows][w*512 .. +512) = xr @ B^T * 2 ----
    short8 xf2[2];
#pragma unroll
    for (int kk = 0; kk < 2; ++kk)
        xf2[kk] = *(const short8*)&xs2[l & 15][kk * 32 + (l >> 4) * 8];
    const int4* bp = (const int4*)Bpk + (size_t)e * 256 * 2 * 64 + l;
    float* ob = out + ((size_t)b * S_ + s0) * OUT_ + w * 512;
    int ro = (l >> 4) * 4, co = l & 15;
#pragma unroll 4
    for (int ntl = 0; ntl < 32; ++ntl) {
        int nt = w * 32 + ntl;
        frag_u bf0, bf1;
        bf0.i4 = bp[((size_t)nt * 2 + 0) * 64];
        bf1.i4 = bp[((size_t)nt * 2 + 1) * 64];
        f32x4 a2 = {};
        a2 = __builtin_amdgcn_mfma_f32_16x16x32_bf16(xf2[0], bf0.s8, a2, 0, 0, 0);
        a2 = __builtin_amdgcn_mfma_f32_16x16x32_bf16(xf2[1], bf1.s8, a2, 0, 0, 0);
#pragma unroll
        for (int i = 0; i < 4; ++i)
            ob[(size_t)(ro + i) * OUT_ + ntl * 16 + co] = a2[i] * SCALING_;
    }
}

extern "C" void kernel_launch(void* const* d_in, const int* in_sizes, int n_in,
                              void* d_out, int out_size, void* d_ws, size_t ws_size,
                              hipStream_t stream) {
    const float* x   = (const float*)d_in[0];
    const float* rel = (const float*)d_in[1];
    const float* reg = (const float*)d_in[2];
    const float* lA  = (const float*)d_in[3];
    const float* lB  = (const float*)d_in[4];
    const float* w1  = (const float*)d_in[5];
    const float* b1  = (const float*)d_in[6];
    const float* w2  = (const float*)d_in[7];
    const float* b2  = (const float*)d_in[8];
    float* out = (float*)d_out;
    float* ws  = (float*)d_ws;

    float*  pp    = ws + WS_PP;
    float*  hacc2 = ws + WS_HACC2;
    int*    top   = (int*)(ws + WS_TOP);
    ushort* Apk   = (ushort*)(ws + WS_APK);
    ushort* Bpk   = (ushort*)(ws + WS_BPK);

    prep_kernel<<<1536, 256, 0, stream>>>(x, lA, lB, pp, Apk, Bpk);
    router_h_kernel<<<dim3(B_, KC_), 256, 0, stream>>>(pp, rel, reg, w1, hacc2);
    router_finish_kernel<<<1, 128, 0, stream>>>(hacc2, b1, w2, b2, top,
                                                out + (size_t)out_size - 1);
    xrout_kernel<<<dim3(S_ / 16, B_), 512, 0, stream>>>(x, Apk, Bpk, top, out);
}